// Round 8
// baseline (913.590 us; speedup 1.0000x reference)
//
#include <hip/hip_runtime.h>

// Problem dims (fixed by reference)
#define S_DIM 2048
#define B_DIM 32
#define H_DIM 1024
#define ROWS  (S_DIM * B_DIM)   // 65536 GEMM rows, row = s*32 + b

typedef __attribute__((ext_vector_type(4))) float    f32x4;
typedef __attribute__((ext_vector_type(8))) _Float16 f16x8;
typedef __attribute__((ext_vector_type(2))) __fp16   h16x2;  // cvt_pkrtz result type

// ---- helpers ----------------------------------------------------------------
__device__ __forceinline__ unsigned short f16_bits(float f) {
  union { _Float16 h; unsigned short u; } cv;
  cv.h = (_Float16)f;           // v_cvt_f16_f32, RNE
  return cv.u;
}

// tanh via one v_exp_f32
__device__ __forceinline__ float fast_tanh(float x) {
  x = fminf(15.0f, fmaxf(-15.0f, x));
  float z = __expf(-2.0f * x);
  return (1.0f - z) * __builtin_amdgcn_rcpf(1.0f + z);
}

// async global->LDS, 16B/lane. LDS dest must be wave-uniform base + lane*16.
__device__ __forceinline__ void load_lds16(const void* g, void* l) {
  __builtin_amdgcn_global_load_lds(
      (const __attribute__((address_space(1))) unsigned int*)g,
      (__attribute__((address_space(3))) unsigned int*)l, 16, 0, 0);
}

// ---- K1 (fused prep): hidproj | packW2 | zero scores | zero ctx --------------
// Bp layout (BK=64 tiled, fp16): [g=h/128][step=k/64][1024 chunks of 16B],
// chunk p = n*8 + (sub ^ (n&7)), sub = (k%64)/8 — conflict-free frag reads.
__global__ void prep_kernel(const float* __restrict__ hidden,
                            const float* __restrict__ attn_w,
                            const float* __restrict__ attn_b,
                            float* __restrict__ hp,
                            unsigned short* __restrict__ Bp,
                            float* __restrict__ scores,
                            float* __restrict__ ctx) {
  int bid = blockIdx.x, tid = threadIdx.x;
  if (bid < 64) {                      // ---- hidproj ----
    int hl = tid >> 4;                 // 0..15
    int kp = tid & 15;                 // 16-way k-split
    int h  = bid * 16 + hl;
    const f32x4* wrow = (const f32x4*)(attn_w + (size_t)h * (2 * H_DIM)) + kp * 16;
    f32x4 w[16];
#pragma unroll
    for (int j = 0; j < 16; ++j) w[j] = wrow[j];
    float bias = attn_b[h];
    for (int b = 0; b < B_DIM; ++b) {
      const f32x4* xrow = (const f32x4*)(hidden + (size_t)b * H_DIM) + kp * 16;
      float s = 0.f;
#pragma unroll
      for (int j = 0; j < 16; ++j) {
        f32x4 x = xrow[j];
        s = fmaf(w[j].x, x.x, s); s = fmaf(w[j].y, x.y, s);
        s = fmaf(w[j].z, x.z, s); s = fmaf(w[j].w, x.w, s);
      }
      s += __shfl_xor(s, 1); s += __shfl_xor(s, 2);
      s += __shfl_xor(s, 4); s += __shfl_xor(s, 8);
      if (kp == 0) hp[(size_t)b * H_DIM + h] = s + bias;
    }
  } else if (bid < 576) {              // ---- packW2 ----
    int id = (bid - 64) * 256 + tid;   // global chunk 0..131071
    int slot = id & 7;
    int n    = (id >> 3) & 127;
    int step = (id >> 10) & 15;
    int g    = id >> 14;
    int sub  = slot ^ (n & 7);
    int h    = g * 128 + n;
    const float* src = attn_w + (size_t)h * (2 * H_DIM) + H_DIM + step * 64 + sub * 8;
    f32x4 a = *(const f32x4*)src;
    f32x4 b = *(const f32x4*)(src + 4);
    ushort4 lo, hi;
    lo.x = f16_bits(a.x); lo.y = f16_bits(a.y); lo.z = f16_bits(a.z); lo.w = f16_bits(a.w);
    hi.x = f16_bits(b.x); hi.y = f16_bits(b.y); hi.z = f16_bits(b.z); hi.w = f16_bits(b.w);
    *(ushort4*)(Bp + (size_t)id * 8)     = lo;
    *(ushort4*)(Bp + (size_t)id * 8 + 4) = hi;
  } else if (bid < 640) {              // ---- zero scores (256 KiB) ----
    int idx = (bid - 576) * 256 + tid;
    *(f32x4*)(scores + (size_t)idx * 4) = (f32x4){0.f, 0.f, 0.f, 0.f};
  } else {                             // ---- zero ctx (128 KiB) ----
    int idx = (bid - 640) * 256 + tid;
    *(f32x4*)(ctx + (size_t)idx * 4) = (f32x4){0.f, 0.f, 0.f, 0.f};
  }
}

// ---- K3: fused cvt + GEMM(enc x W2^T) + tanh + dot-v -> scores ---------------
// 128x128 tile, BK=64, 256 thr = 4 waves (2x2), wave 64x64 via 4x4 16x16x32
// f16 frags x 2 k-halves.
//   A: direct global->register fp32 loads in MFMA A-layout (A[m=lane&15]
//      [k=quad*8+j]) + cvt_pkrtz — NO LDS traffic for A. Per frag-load, the
//      4 quads of one m16 cover one contiguous 128B line -> full-line reqs;
//      XCD colocation makes the 8-block A reuse L2-local.
//   B: LDS double-buffer; DMA(step+1) issued right after the barrier so the
//      next barrier's vmcnt drain finds it complete (~620 MFMA cyc later).
__global__ __launch_bounds__(256, 3)
void gemm_scores_kernel(const float* __restrict__ enc,
                        const unsigned short* __restrict__ Bp,
                        const float* __restrict__ hp,
                        const float* __restrict__ v,
                        float* __restrict__ scores) {
  __shared__ __align__(16) unsigned short Bs[2][1024 * 8];   // 2 x 16 KiB
  const int tid  = threadIdx.x;
  const int lane = tid & 63;
  const int wid  = tid >> 6;
  const int wm   = wid >> 1;       // row half (0..1)
  const int wn   = wid & 1;        // col half (0..1)
  const int m16  = lane & 15;
  const int quad = lane >> 4;
  const int rx   = m16 & 7;        // B swizzle key (n&7 == m16&7 for all frags)
  // XCD-colocating decode
  const int bid  = blockIdx.x;
  const int xcd  = bid & 7;
  const int slot = bid >> 3;               // 0..511
  const int t    = xcd * 64 + (slot >> 3); // row tile 0..511
  const int g    = slot & 7;               // col tile 0..7

  f32x4 acc[4][4];
#pragma unroll
  for (int i = 0; i < 4; ++i)
#pragma unroll
    for (int j = 0; j < 4; ++j) acc[i][j] = (f32x4){0.f, 0.f, 0.f, 0.f};

  const float* aBase = enc + (size_t)t * 128 * H_DIM;
  const unsigned short* bBase = Bp + (size_t)g * 16 * 8192;

  // Per-frag A base offsets (float index): row r_f = wm*64 + f*16 + m16
  size_t aOff[4];
#pragma unroll
  for (int f = 0; f < 4; ++f)
    aOff[f] = (size_t)(wm * 64 + f * 16 + m16) * H_DIM + quad * 8;

  // Prime B double-buffer with step 0
  {
    const unsigned short* bS = bBase;
#pragma unroll
    for (int c = 0; c < 4; ++c) {
      int q = c * 256 + tid;
      load_lds16(bS + (size_t)q * 8, &Bs[0][q * 8]);
    }
  }

  for (int step = 0; step < 16; ++step) {
    __syncthreads();               // B(step) DMA complete; prev buf free
    if (step < 15) {               // prefetch B(step+1) into alternate buffer
      const unsigned short* bS = bBase + (size_t)(step + 1) * 8192;
      unsigned short* dstb = &Bs[(step + 1) & 1][0];
#pragma unroll
      for (int c = 0; c < 4; ++c) {
        int q = c * 256 + tid;
        load_lds16(bS + (size_t)q * 8, dstb + q * 8);
      }
    }
    const unsigned short* bsb = &Bs[step & 1][0];
    const float* aStep = aBase + step * 64;

#pragma unroll
    for (int ko = 0; ko < 2; ++ko) {
      // A: 8 direct global loads (fp32), in-register cvt to 4 frags
      f32x4 a0[4], a1[4];
#pragma unroll
      for (int f = 0; f < 4; ++f) {
        const float* ap = aStep + aOff[f] + ko * 32;
        a0[f] = *(const f32x4*)ap;
        a1[f] = *(const f32x4*)(ap + 4);
      }
      // B frags from LDS (conflict-free swizzled slots)
      int sl = (ko * 4 + quad) ^ rx;
      f16x8 bfr[4];
#pragma unroll
      for (int f = 0; f < 4; ++f) {
        int n = wn * 64 + f * 16 + m16;
        bfr[f] = *(const f16x8*)&bsb[n * 64 + sl * 8];
      }
#pragma unroll
      for (int mf = 0; mf < 4; ++mf) {
        union { f16x8 v8; h16x2 h2[4]; } pk;
        pk.h2[0] = __builtin_amdgcn_cvt_pkrtz(a0[mf].x, a0[mf].y);
        pk.h2[1] = __builtin_amdgcn_cvt_pkrtz(a0[mf].z, a0[mf].w);
        pk.h2[2] = __builtin_amdgcn_cvt_pkrtz(a1[mf].x, a1[mf].y);
        pk.h2[3] = __builtin_amdgcn_cvt_pkrtz(a1[mf].z, a1[mf].w);
#pragma unroll
        for (int nf = 0; nf < 4; ++nf)
          acc[mf][nf] = __builtin_amdgcn_mfma_f32_16x16x32_f16(
              pk.v8, bfr[nf], acc[mf][nf], 0, 0, 0);
      }
    }
  }

  // Epilogue: energy = tanh(acc + hid_proj(incl bias)); partial score =
  // sum over this wave's 64 cols of energy*v. C/D: col=lane&15, row=quad*4+reg.
  const int row0 = t * 128, n0 = g * 128;
#pragma unroll
  for (int mf = 0; mf < 4; ++mf) {
#pragma unroll
    for (int reg = 0; reg < 4; ++reg) {
      int row_g = row0 + wm * 64 + mf * 16 + quad * 4 + reg;
      int b     = row_g & 31;     // row = s*32 + b
      int s     = row_g >> 5;
      float psum = 0.f;
#pragma unroll
      for (int nf = 0; nf < 4; ++nf) {
        int col = n0 + wn * 64 + nf * 16 + m16;
        float e = acc[mf][nf][reg] + hp[b * H_DIM + col];
        e = fast_tanh(e);
        psum = fmaf(e, v[col], psum);
      }
      psum += __shfl_xor(psum, 1);
      psum += __shfl_xor(psum, 2);
      psum += __shfl_xor(psum, 4);
      psum += __shfl_xor(psum, 8);
      if (m16 == 0) atomicAdd(&scores[b * S_DIM + s], psum);
    }
  }
}

// ---- K4: masked softmax over s per batch row -> attention weights ------------
__global__ void softmax_kernel(const float* __restrict__ scores,
                               const int* __restrict__ lens,
                               float* __restrict__ wout) {
  int b = blockIdx.x, tid = threadIdx.x;
  int len = lens[b];
  float vals[8];
  float m = -3.0e38f;
#pragma unroll
  for (int i = 0; i < 8; ++i) {
    int s = i * 256 + tid;
    float x = scores[b * S_DIM + s];
    vals[i] = (s < len) ? x : -3.0e38f;
    m = fmaxf(m, vals[i]);
  }
#pragma unroll
  for (int off = 32; off > 0; off >>= 1) m = fmaxf(m, __shfl_xor(m, off));
  __shared__ float redm[4], reds[4];
  int wid = tid >> 6, lane = tid & 63;
  if (lane == 0) redm[wid] = m;
  __syncthreads();
  m = fmaxf(fmaxf(redm[0], redm[1]), fmaxf(redm[2], redm[3]));

  float e[8];
  float sum = 0.f;
#pragma unroll
  for (int i = 0; i < 8; ++i) {
    int s = i * 256 + tid;
    e[i] = (s < len) ? __expf(vals[i] - m) : 0.f;  // masked -> exactly 0
    sum += e[i];
  }
#pragma unroll
  for (int off = 32; off > 0; off >>= 1) sum += __shfl_xor(sum, off);
  if (lane == 0) reds[wid] = sum;
  __syncthreads();
  sum = reds[0] + reds[1] + reds[2] + reds[3];
  float inv = 1.0f / sum;
#pragma unroll
  for (int i = 0; i < 8; ++i)
    wout[b * S_DIM + i * 256 + tid] = e[i] * inv;
}

// ---- K5: context[b][h] = sum_s w[b][s] * enc[s][b][h]  (fp32, full-row reads)
// 16 s-chunks x 32 b; prefix mask -> block-level skip; one 4-KB coalesced row
// read per iteration; 4 atomics per thread at the end.
__global__ void context_kernel(const float* __restrict__ enc,
                               const float* __restrict__ wts,
                               const int* __restrict__ lens,
                               float* __restrict__ ctx) {
  int sc = blockIdx.x;            // 0..15, 128 s each
  int b  = blockIdx.y;
  int len = lens[b];
  int s0 = sc * 128;
  if (s0 >= len) return;          // fully masked chunk (weights exactly 0)
  int cnt = min(128, len - s0);
  int tid = threadIdx.x;          // 256 threads x 4 h = 1024
  f32x4 acc = (f32x4){0.f, 0.f, 0.f, 0.f};
  const float* wrow = wts + (size_t)b * S_DIM + s0;
#pragma unroll 4
  for (int i = 0; i < cnt; ++i) {
    float w = wrow[i];
    f32x4 e = *(const f32x4*)(enc + ((size_t)(s0 + i) * B_DIM + b) * H_DIM + tid * 4);
    acc.x = fmaf(w, e.x, acc.x);
    acc.y = fmaf(w, e.y, acc.y);
    acc.z = fmaf(w, e.z, acc.z);
    acc.w = fmaf(w, e.w, acc.w);
  }
  float* dst = ctx + (size_t)b * H_DIM + tid * 4;
  atomicAdd(dst + 0, acc.x);
  atomicAdd(dst + 1, acc.y);
  atomicAdd(dst + 2, acc.z);
  atomicAdd(dst + 3, acc.w);
}

// ---- launch -----------------------------------------------------------------
extern "C" void kernel_launch(void* const* d_in, const int* in_sizes, int n_in,
                              void* d_out, int out_size, void* d_ws, size_t ws_size,
                              hipStream_t stream) {
  const float* hidden = (const float*)d_in[0];   // (B,H)
  const float* enc    = (const float*)d_in[1];   // (S,B,H)
  const int*   lens   = (const int*)d_in[2];     // (B,)
  const float* attn_w = (const float*)d_in[3];   // (H,2H)
  const float* attn_b = (const float*)d_in[4];   // (H,)
  const float* v      = (const float*)d_in[5];   // (H,)

  float* out_ctx = (float*)d_out;                      // B*H context
  float* out_w   = (float*)d_out + B_DIM * H_DIM;      // B*S weights

  // ws: scores (256 KiB) | hp (128 KiB) | Bp fp16 tiled (2 MiB)
  char* p = (char*)d_ws;
  float* scores = (float*)p;               p += (size_t)B_DIM * S_DIM * 4;
  float* hp     = (float*)p;               p += (size_t)B_DIM * H_DIM * 4;
  unsigned short* Bp = (unsigned short*)p;

  hipLaunchKernelGGL(prep_kernel, dim3(672), dim3(256), 0, stream,
                     hidden, attn_w, attn_b, hp, Bp, scores, out_ctx);
  hipLaunchKernelGGL(gemm_scores_kernel, dim3(4096), dim3(256), 0, stream,
                     enc, Bp, hp, v, scores);
  hipLaunchKernelGGL(softmax_kernel, dim3(B_DIM), dim3(256), 0, stream,
                     scores, lens, out_w);
  hipLaunchKernelGGL(context_kernel, dim3(16, B_DIM), dim3(256), 0, stream,
                     enc, out_w, lens, out_ctx);
}